// Round 3
// baseline (689.267 us; speedup 1.0000x reference)
//
#include <hip/hip_runtime.h>

// VertexSplitter: B=256, V=512.
// out = (M > 0) where M = (Pid > 0) with 8 per-batch conditional edits.
// Output is (out, out) concatenated -> 2 * B*V*V floats.
//
// R3: per-wave 1R:1W restructure of fill_kernel.
//  - R2 post-mortem: nt 1R:2W kernel stuck at ~2.5 TB/s combined while
//    pure-write (poison fill) and 1R:1W (m13 copy) both hit ~6.3 TB/s.
//    Theory: 3 interleaved far-apart streams per wave is the cap.
//  - Now each block owns ONE (chunk, copy) pair: clean 1R:1W per wave.
//    Blocks d and d+8 process the same chunk for copy0/copy1; round-robin
//    dispatch puts both on XCD d%8 at ~the same time, so the duplicate
//    Pid read is served by the 4 MiB XCD L2 / merged in-flight (no extra
//    HBM fetch). HBM floor stays 268R + 537W = 805 MB ~= 128 us.
//  - Stores are nontemporal (no reuse, keep L2 clean for read pairing);
//    loads are normal cached loads (MUST allocate in L2 for the pairing).

#define BATCH 256
#define VDIM 512
#define UNROLL 4
#define CHUNK_F4 (256 * UNROLL)   // float4s per chunk = 1024 (16 KiB)

typedef float floatx4 __attribute__((ext_vector_type(4)));

__global__ void __launch_bounds__(256) fill_kernel(const floatx4* __restrict__ pid,
                                                   floatx4* __restrict__ out,
                                                   long long n4) {
    // 32768 blocks. Group of 16 consecutive blocks g covers chunks
    // [8g, 8g+8) twice: sub 0..7 -> copy0, sub 8..15 -> copy1.
    // Blocks d=16g+s and d+8 share a chunk AND an XCD (d % 8 == (d+8) % 8).
    unsigned d   = blockIdx.x;
    unsigned g   = d >> 4;
    unsigned sub = d & 15;
    long long chunk   = (long long)g * 8 + (sub & 7);
    long long copyoff = (sub >> 3) ? n4 : 0;
    long long base    = chunk * CHUNK_F4 + threadIdx.x;

    floatx4 p[UNROLL];
#pragma unroll
    for (int u = 0; u < UNROLL; ++u) {
        p[u] = pid[base + u * 256];           // cached load (L2 pairing)
    }

#pragma unroll
    for (int u = 0; u < UNROLL; ++u) {
        floatx4 o;
        o.x = p[u].x > 0.f ? 1.f : 0.f;
        o.y = p[u].y > 0.f ? 1.f : 0.f;
        o.z = p[u].z > 0.f ? 1.f : 0.f;
        o.w = p[u].w > 0.f ? 1.f : 0.f;
        __builtin_nontemporal_store(o, &out[base + u * 256 + copyoff]);
    }
}

__global__ void __launch_bounds__(256) edit_kernel(const float* __restrict__ pid,
                                                   const int* __restrict__ inter,
                                                   float* __restrict__ out,
                                                   long long n) {
    int b = blockIdx.x * blockDim.x + threadIdx.x;
    if (b >= BATCH) return;

    int e10 = inter[b * 4 + 0];
    int e11 = inter[b * 4 + 1];
    int e20 = inter[b * 4 + 2];
    int e21 = inter[b * 4 + 3];

    bool distinct = (e10 != e11) && (e10 != e20) && (e10 != e21) &&
                    (e11 != e20) && (e11 != e21) && (e20 != e21);

    const float* P = pid + (long long)b * VDIM * VDIM;
    // blocked / old_pid read from ORIGINAL M = (Pid > 0), before any edits
    bool blocked = (P[(long long)e10 * VDIM + e20] > 0.f) ||
                   (P[(long long)e11 * VDIM + e21] > 0.f);
    bool valid = distinct && !blocked;
    if (!valid) return;

    float old_pid = (P[(long long)e10 * VDIM + e11] > 0.f) ? 1.f : 0.f;

    float* O0 = out + (long long)b * VDIM * VDIM;
    float* O1 = O0 + n;

    // All 8 ordered positions are distinct when valid (4 distinct vertices),
    // so the sequential csets reduce to independent stores.
    long long i_1011 = (long long)e10 * VDIM + e11;
    long long i_1110 = (long long)e11 * VDIM + e10;
    long long i_2021 = (long long)e20 * VDIM + e21;
    long long i_2120 = (long long)e21 * VDIM + e20;
    long long i_1020 = (long long)e10 * VDIM + e20;
    long long i_2010 = (long long)e20 * VDIM + e10;
    long long i_1121 = (long long)e11 * VDIM + e21;
    long long i_2111 = (long long)e21 * VDIM + e11;

    O0[i_1011] = 0.f;      O1[i_1011] = 0.f;
    O0[i_1110] = 0.f;      O1[i_1110] = 0.f;
    O0[i_2021] = 0.f;      O1[i_2021] = 0.f;
    O0[i_2120] = 0.f;      O1[i_2120] = 0.f;
    O0[i_1020] = old_pid;  O1[i_1020] = old_pid;
    O0[i_2010] = old_pid;  O1[i_2010] = old_pid;
    O0[i_1121] = 1.f;      O1[i_1121] = 1.f;
    O0[i_2111] = 1.f;      O1[i_2111] = 1.f;
}

extern "C" void kernel_launch(void* const* d_in, const int* in_sizes, int n_in,
                              void* d_out, int out_size, void* d_ws, size_t ws_size,
                              hipStream_t stream) {
    const float* pid  = (const float*)d_in[0];   // (B, V, V) float32
    const int* inter  = (const int*)d_in[1];     // (B, 2, 2) int32
    float* out        = (float*)d_out;           // 2 * B*V*V float32

    long long n  = (long long)BATCH * VDIM * VDIM;  // 67,108,864
    long long n4 = n / 4;                           // 16,777,216 float4s

    dim3 block(256);
    // 16384 chunks * 2 copies = 32768 blocks, exact divide.
    dim3 grid((unsigned)((n4 / CHUNK_F4) * 2));
    fill_kernel<<<grid, block, 0, stream>>>((const floatx4*)pid, (floatx4*)out, n4);
    edit_kernel<<<1, 256, 0, stream>>>(pid, inter, out, n);
}

// Round 4
// 670.811 us; speedup vs baseline: 1.0275x; 1.0275x over previous
//
#include <hip/hip_runtime.h>

// VertexSplitter: B=256, V=512.
// out = (M > 0) where M = (Pid > 0) with 8 per-batch conditional edits.
// Output is (out, out) concatenated -> 2 * B*V*V floats.
//
// R4: single fused kernel.
//  - R0/R2/R3 post-mortem: three structurally different fill kernels
//    (1R:2W plain, nt+MLP, per-block 1R:1W copy-pattern) all land at
//    674-689 us (+-1%). The window is dominated by fixed harness cost
//    (one 2 GiB poison fill @6.25 TB/s = ~340 us/iter is visible in the
//    profile, plus restore/launch overhead); our fill is already at or
//    near its 768 MiB => ~122-170 us roofline.
//  - Only lever left that we own: dispatch count + the serial 1-block
//    edit tail. Fuse the edit into the fill:
//      * each block covers 2 rows of one batch (256 thr * 4 floats
//        = 1024 floats = 2 rows of V=512); 256 blocks per batch.
//      * edits only touch rows {e10,e11,e20,e21} -> only blocks whose
//        2 rows intersect that set (~4/256 per batch) take the patch
//        path. The rowmatch branch is block-uniform (no divergence).
//      * patch writes use compile-time vector components (no runtime
//        indexing into float4 -> no scratch).
//  - Stores back to plain cached float4 (R0 variant was fastest).

#define BATCH 256
#define VDIM 512

__global__ void __launch_bounds__(256) fused_kernel(const float4* __restrict__ pid,
                                                    const int* __restrict__ inter,
                                                    float4* __restrict__ out,
                                                    long long n4) {
    long long i = (long long)blockIdx.x * 256 + threadIdx.x;   // float4 index

    float4 p = pid[i];
    float4 o;
    o.x = p.x > 0.f ? 1.f : 0.f;
    o.y = p.y > 0.f ? 1.f : 0.f;
    o.z = p.z > 0.f ? 1.f : 0.f;
    o.w = p.w > 0.f ? 1.f : 0.f;

    // --- fused edit patch -------------------------------------------------
    // Block covers rows r0, r0+1 (r0 even) of batch b.
    int blk = blockIdx.x;
    int b   = blk >> 8;          // 256 blocks per batch
    int rhi = blk & 255;         // row-pair index = r0 >> 1

    // 16B uniform load; address is lane-invariant -> scalarized / broadcast.
    int e10 = inter[b * 4 + 0];
    int e11 = inter[b * 4 + 1];
    int e20 = inter[b * 4 + 2];
    int e21 = inter[b * 4 + 3];

    bool rowmatch = ((e10 >> 1) == rhi) | ((e11 >> 1) == rhi) |
                    ((e20 >> 1) == rhi) | ((e21 >> 1) == rhi);

    if (rowmatch) {  // block-uniform branch; ~4/256 blocks per batch
        bool distinct = (e10 != e11) && (e10 != e20) && (e10 != e21) &&
                        (e11 != e20) && (e11 != e21) && (e20 != e21);
        const float* P = (const float*)pid + (long long)b * VDIM * VDIM;
        bool blocked = (P[(long long)e10 * VDIM + e20] > 0.f) ||
                       (P[(long long)e11 * VDIM + e21] > 0.f);
        bool valid = distinct && !blocked;

        if (valid) {
            float old_pid = (P[(long long)e10 * VDIM + e11] > 0.f) ? 1.f : 0.f;

            // 8 edit positions (all distinct when valid).
            int   er[8] = { e10, e11, e20, e21, e10, e20, e11, e21 };
            int   ec[8] = { e11, e10, e21, e20, e20, e10, e21, e11 };
            float ev[8] = { 0.f, 0.f, 0.f, 0.f, old_pid, old_pid, 1.f, 1.f };

            int r0 = rhi * 2;
            int base_local = threadIdx.x * 4;   // this thread's first local float
#pragma unroll
            for (int k = 0; k < 8; ++k) {
                int rl = er[k] - r0;            // 0 or 1 if in this block
                if (rl == 0 || rl == 1) {
                    int local = rl * VDIM + ec[k];   // 0..1023 within block
                    if (local == base_local + 0) o.x = ev[k];
                    if (local == base_local + 1) o.y = ev[k];
                    if (local == base_local + 2) o.z = ev[k];
                    if (local == base_local + 3) o.w = ev[k];
                }
            }
        }
    }
    // ----------------------------------------------------------------------

    out[i]      = o;   // copy 0
    out[i + n4] = o;   // copy 1
}

extern "C" void kernel_launch(void* const* d_in, const int* in_sizes, int n_in,
                              void* d_out, int out_size, void* d_ws, size_t ws_size,
                              hipStream_t stream) {
    const float* pid  = (const float*)d_in[0];   // (B, V, V) float32
    const int* inter  = (const int*)d_in[1];     // (B, 2, 2) int32
    float* out        = (float*)d_out;           // 2 * B*V*V float32

    long long n  = (long long)BATCH * VDIM * VDIM;  // 67,108,864
    long long n4 = n / 4;                           // 16,777,216 float4s

    dim3 block(256);
    dim3 grid((unsigned)(n4 / 256));                // 65,536 blocks, exact
    fused_kernel<<<grid, block, 0, stream>>>((const float4*)pid, inter,
                                             (float4*)out, n4);
}